// Round 7
// baseline (614.160 us; speedup 1.0000x reference)
//
#include <hip/hip_runtime.h>
#include <hip/hip_cooperative_groups.h>

namespace cg = cooperative_groups;

// Problem constants (from reference setup_inputs):
//   B=8, T=4096, x0:[8,1024,4096] f32, x1:[8,768,4096] f32
//   BC=256, RC=64, NB0=4, NB1=3, TB=7, EPS=1e-5, LOWEST=0
#define B_SZ 8
#define T_SZ 4096
#define BC 256
#define RC 64
#define NB0 4
#define NB1 3
#define TB 7
#define ROWS0 (B_SZ * 1024)            // 8192 rows in x0
#define ROWS1 (B_SZ * 768)             // 6144 rows in x1
#define ROWS_TOTAL (ROWS0 + ROWS1)     // 14336
#define X0_ELEMS (33554432ull)         // 8*1024*4096
#define MAX_COOP_BLOCKS 1792           // 2 rows/wave; more is useless

// Native vector type: __builtin_nontemporal_{load,store} rejects
// HIP_vector_type (float4 is a class); ext_vector_type is bit-identical.
typedef float vfloat4 __attribute__((ext_vector_type(4)));

// ---------------------------------------------------------------------------
// Fused cooperative kernel, three phases separated by grid.sync().
// Grid-stride over rows in P1/P3 so ANY grid size >= 8 blocks is correct;
// the host sizes the grid from a real occupancy query (round-6 lesson:
// a too-large cooperative grid fails to launch entirely).
// __launch_bounds__(256,4): guarantee >=4 blocks/CU (VGPR cap 128).
// ---------------------------------------------------------------------------
__global__ __launch_bounds__(256, 4) void fused_kernel(const float* __restrict__ x0,
                                                       const float* __restrict__ x1,
                                                       const float* __restrict__ W1,
                                                       const float* __restrict__ b1,
                                                       const float* __restrict__ gamma,
                                                       const float* __restrict__ beta,
                                                       const float* __restrict__ Wh,
                                                       const float* __restrict__ bh,
                                                       float* __restrict__ out,
                                                       float* __restrict__ att) {
    __shared__ float s_gap[BC];
    __shared__ float s_h[RC];

    const int tid    = threadIdx.x;
    const int lane   = tid & 63;
    const int nwaves = gridDim.x * 4;
    const int wid0   = blockIdx.x * 4 + (tid >> 6);
    float* rowsum = out;                            // scratch in out-prefix

    // ---------------- Phase 1: rowsum (one wave per row, grid-stride) ------
    for (int row = wid0; row < ROWS_TOTAL; row += nwaves) {
        const float4* src = (row < ROWS0)
            ? (const float4*)(x0 + (size_t)row * T_SZ)
            : (const float4*)(x1 + (size_t)(row - ROWS0) * T_SZ);
        float sum = 0.0f;
#pragma unroll
        for (int it = 0; it < 16; ++it) {
            float4 v = src[it * 64 + lane];
            sum += (v.x + v.y) + (v.z + v.w);
        }
#pragma unroll
        for (int off = 32; off > 0; off >>= 1)
            sum += __shfl_down(sum, off, 64);
        if (lane == 0)
            rowsum[row] = sum;
    }

    cg::this_grid().sync();

    // ---------------- Phase 2: att weights (blocks 0..7 only) --------------
    if (blockIdx.x < B_SZ) {
        const int b = blockIdx.x;
        float s = 0.0f;
#pragma unroll
        for (int blk = 0; blk < NB0; ++blk)
            s += rowsum[b * 1024 + blk * 256 + tid];
#pragma unroll
        for (int blk = 0; blk < NB1; ++blk)
            s += rowsum[ROWS0 + b * 768 + blk * 256 + tid];
        s_gap[tid] = s * (1.0f / (float)T_SZ);
        __syncthreads();

        if (tid < RC) {
            const float bnscale = rsqrtf(1.0f + 1e-5f);
            float acc = 0.0f;
#pragma unroll 8
            for (int c = 0; c < BC; ++c)
                acc = fmaf(s_gap[c], W1[c * RC + tid], acc);
            acc += b1[tid];
            acc = acc * (gamma[tid] * bnscale) + beta[tid];
            s_h[tid] = fmaxf(acc, 0.0f);
        }
        __syncthreads();

        float sc[TB];
#pragma unroll
        for (int k = 0; k < TB; ++k)
            sc[k] = bh[k * BC + tid];
        for (int r = 0; r < RC; ++r) {
            const float hr = s_h[r];
#pragma unroll
            for (int k = 0; k < TB; ++k)
                sc[k] = fmaf(Wh[(k * RC + r) * BC + tid], hr, sc[k]);
        }
        float mx = -1e30f;
#pragma unroll
        for (int k = 0; k < TB; ++k) mx = fmaxf(mx, sc[k]);
        float sum = 0.0f;
#pragma unroll
        for (int k = 0; k < TB; ++k) { sc[k] = __expf(sc[k] - mx); sum += sc[k]; }
        const float inv = 1.0f / sum;
#pragma unroll
        for (int k = 0; k < TB; ++k)
            att[(b * TB + k) * BC + tid] = sc[k] * inv;   // LOWEST=0
    }

    cg::this_grid().sync();

    // ---------------- Phase 3: scale (one wave per row, grid-stride) -------
    for (int row = wid0; row < ROWS_TOTAL; row += nwaves) {
        const vfloat4* src;
        vfloat4* dst;
        float a;
        if (row < ROWS0) {
            const int b = row >> 10;
            const int ch = row & 1023;
            a = att[(b * TB + (ch >> 8)) * BC + (ch & 255)];
            src = (const vfloat4*)(x0 + (size_t)row * T_SZ);
            dst = (vfloat4*)(out + (size_t)row * T_SZ);
        } else {
            const int r = row - ROWS0;
            const int b = (int)((unsigned)r / 768u);
            const int ch = r - b * 768;
            a = att[(b * TB + NB0 + (ch >> 8)) * BC + (ch & 255)];
            src = (const vfloat4*)(x1 + (size_t)r * T_SZ);
            dst = (vfloat4*)(out + X0_ELEMS + (size_t)r * T_SZ);
        }
#pragma unroll
        for (int it = 0; it < 16; ++it) {
            vfloat4 v = __builtin_nontemporal_load(&src[it * 64 + lane]);
            v *= a;
            __builtin_nontemporal_store(v, &dst[it * 64 + lane]);
        }
    }
}

// ---------------------------------------------------------------------------
// Fallback path: the proven round-5 three-kernel pipeline (449 us), used if
// the cooperative launch cannot run.
// ---------------------------------------------------------------------------
__global__ __launch_bounds__(256) void rowsum_kernel(const float* __restrict__ x0,
                                                     const float* __restrict__ x1,
                                                     float* __restrict__ rowsum) {
    const int gtid = blockIdx.x * 256 + threadIdx.x;
    const int wave = gtid >> 6;
    const int lane = threadIdx.x & 63;
    const float4* src = (wave < ROWS0)
        ? (const float4*)(x0 + (size_t)wave * T_SZ)
        : (const float4*)(x1 + (size_t)(wave - ROWS0) * T_SZ);
    float sum = 0.0f;
#pragma unroll
    for (int it = 0; it < 16; ++it) {
        float4 v = src[it * 64 + lane];
        sum += (v.x + v.y) + (v.z + v.w);
    }
#pragma unroll
    for (int off = 32; off > 0; off >>= 1)
        sum += __shfl_down(sum, off, 64);
    if (lane == 0)
        rowsum[wave] = sum;
}

__global__ __launch_bounds__(256) void att_kernel(const float* __restrict__ rowsum,
                                                  const float* __restrict__ W1,
                                                  const float* __restrict__ b1,
                                                  const float* __restrict__ gamma,
                                                  const float* __restrict__ beta,
                                                  const float* __restrict__ Wh,
                                                  const float* __restrict__ bh,
                                                  float* __restrict__ att) {
    __shared__ float s_gap[BC];
    __shared__ float s_h[RC];
    const int tid = threadIdx.x;
    const int b = blockIdx.x;
    float s = 0.0f;
#pragma unroll
    for (int blk = 0; blk < NB0; ++blk)
        s += rowsum[b * 1024 + blk * 256 + tid];
#pragma unroll
    for (int blk = 0; blk < NB1; ++blk)
        s += rowsum[ROWS0 + b * 768 + blk * 256 + tid];
    s_gap[tid] = s * (1.0f / (float)T_SZ);
    __syncthreads();
    if (tid < RC) {
        const float bnscale = rsqrtf(1.0f + 1e-5f);
        float acc = 0.0f;
#pragma unroll 8
        for (int c = 0; c < BC; ++c)
            acc = fmaf(s_gap[c], W1[c * RC + tid], acc);
        acc += b1[tid];
        acc = acc * (gamma[tid] * bnscale) + beta[tid];
        s_h[tid] = fmaxf(acc, 0.0f);
    }
    __syncthreads();
    float sc[TB];
#pragma unroll
    for (int k = 0; k < TB; ++k)
        sc[k] = bh[k * BC + tid];
    for (int r = 0; r < RC; ++r) {
        const float hr = s_h[r];
#pragma unroll
        for (int k = 0; k < TB; ++k)
            sc[k] = fmaf(Wh[(k * RC + r) * BC + tid], hr, sc[k]);
    }
    float mx = -1e30f;
#pragma unroll
    for (int k = 0; k < TB; ++k) mx = fmaxf(mx, sc[k]);
    float sum = 0.0f;
#pragma unroll
    for (int k = 0; k < TB; ++k) { sc[k] = __expf(sc[k] - mx); sum += sc[k]; }
    const float inv = 1.0f / sum;
#pragma unroll
    for (int k = 0; k < TB; ++k)
        att[(b * TB + k) * BC + tid] = sc[k] * inv;
}

__global__ __launch_bounds__(256) void scale_kernel(const float* __restrict__ x0,
                                                    const float* __restrict__ x1,
                                                    const float* __restrict__ att,
                                                    float* __restrict__ out) {
    const int row = blockIdx.x * 4 + (threadIdx.x >> 6);
    const int lane = threadIdx.x & 63;
    const vfloat4* src;
    vfloat4* dst;
    float a;
    if (row < ROWS0) {
        const int b = row >> 10;
        const int ch = row & 1023;
        a = att[(b * TB + (ch >> 8)) * BC + (ch & 255)];
        src = (const vfloat4*)(x0 + (size_t)row * T_SZ);
        dst = (vfloat4*)(out + (size_t)row * T_SZ);
    } else {
        const int r = row - ROWS0;
        const int b = (int)((unsigned)r / 768u);
        const int ch = r - b * 768;
        a = att[(b * TB + NB0 + (ch >> 8)) * BC + (ch & 255)];
        src = (const vfloat4*)(x1 + (size_t)r * T_SZ);
        dst = (vfloat4*)(out + X0_ELEMS + (size_t)r * T_SZ);
    }
#pragma unroll
    for (int it = 0; it < 16; ++it) {
        vfloat4 v = __builtin_nontemporal_load(&src[it * 64 + lane]);
        v *= a;
        __builtin_nontemporal_store(v, &dst[it * 64 + lane]);
    }
}

extern "C" void kernel_launch(void* const* d_in, const int* in_sizes, int n_in,
                              void* d_out, int out_size, void* d_ws, size_t ws_size,
                              hipStream_t stream) {
    const float* x0    = (const float*)d_in[0];
    const float* x1    = (const float*)d_in[1];
    const float* W1    = (const float*)d_in[2];
    const float* b1    = (const float*)d_in[3];
    const float* gamma = (const float*)d_in[4];
    const float* beta  = (const float*)d_in[5];
    const float* Wh    = (const float*)d_in[6];
    const float* bh    = (const float*)d_in[7];
    float* out = (float*)d_out;
    float* att = (float*)d_ws;     // 56 KiB, within proven workspace budget

    // Size the cooperative grid from a real occupancy query (host-side only,
    // graph-capture safe; cached). Round-6 lesson: an oversubscribed
    // cooperative grid silently refuses to launch.
    static int coop_blocks = -1;
    if (coop_blocks < 0) {
        int per_cu = 0, n_cu = 0, dev = 0;
        hipError_t e0 = hipGetDevice(&dev);
        hipError_t e1 = hipOccupancyMaxActiveBlocksPerMultiprocessor(
                            &per_cu, (const void*)fused_kernel, 256, 0);
        hipError_t e2 = hipDeviceGetAttribute(
                            &n_cu, hipDeviceAttributeMultiprocessorCount, dev);
        if (e0 == hipSuccess && e1 == hipSuccess && e2 == hipSuccess &&
            per_cu > 0 && n_cu > 0) {
            long total = (long)per_cu * (long)n_cu;
            coop_blocks = (int)(total > MAX_COOP_BLOCKS ? MAX_COOP_BLOCKS : total);
        } else {
            coop_blocks = 0;
        }
    }

    if (coop_blocks >= B_SZ) {
        void* args[] = {(void*)&x0, (void*)&x1, (void*)&W1, (void*)&b1,
                        (void*)&gamma, (void*)&beta, (void*)&Wh, (void*)&bh,
                        (void*)&out, (void*)&att};
        hipError_t err = hipLaunchCooperativeKernel((const void*)fused_kernel,
                                                    dim3(coop_blocks), dim3(256),
                                                    args, 0, stream);
        if (err == hipSuccess)
            return;
    }

    // Fallback: proven three-kernel pipeline (rowsum scratch in out-prefix).
    float* rowsum = out;
    rowsum_kernel<<<ROWS_TOTAL / 4, 256, 0, stream>>>(x0, x1, rowsum);
    att_kernel<<<B_SZ, 256, 0, stream>>>(rowsum, W1, b1, gamma, beta, Wh, bh, att);
    scale_kernel<<<ROWS_TOTAL / 4, 256, 0, stream>>>(x0, x1, att, out);
}

// Round 8
// 561.433 us; speedup vs baseline: 1.0939x; 1.0939x over previous
//
#include <hip/hip_runtime.h>

// Problem constants (from reference setup_inputs):
//   B=8, T=4096, x0:[8,1024,4096] f32, x1:[8,768,4096] f32
//   BC=256, RC=64, NB0=4, NB1=3, TB=7, EPS=1e-5, LOWEST=0
#define B_SZ 8
#define T_SZ 4096
#define BC 256
#define RC 64
#define NB0 4
#define NB1 3
#define TB 7
#define ROWS0 (B_SZ * 1024)            // 8192 rows in x0
#define ROWS1 (B_SZ * 768)             // 6144 rows in x1
#define ROWS_TOTAL (ROWS0 + ROWS1)     // 14336
#define X0_ELEMS (33554432ull)         // 8*1024*4096

// Native vector type: __builtin_nontemporal_{load,store} rejects
// HIP_vector_type (float4 is a class); ext_vector_type is bit-identical.
typedef float vfloat4 __attribute__((ext_vector_type(4)));

// ===========================================================================
// MEASUREMENT ROUND: exact round-5 pipeline (449 us, best so far), but
// rowsum and scale are each launched TWICE (idempotent -- identical writes),
// so  dur_R8 - dur_R5 = rowsum_dur + scale_dur.  This pins the split between
// our kernels and harness-fixed overhead, which decides ROOFLINE vs continue.
// Round-7 lesson: cooperative fusion degrades streaming BW ~4x; reverted.
// ===========================================================================

// ---------------------------------------------------------------------------
// Kernel 1: per-row sum over time -> rowsum[row] (scratch in out-prefix).
// One wave per row: 16 x (1 KiB contiguous per wave). Plain loads on purpose:
// they allocate x in L3, which serves scale's re-read (confirmed by R7's
// FETCH_SIZE = 225 MB for 470 MB of demand reads).
// ---------------------------------------------------------------------------
__global__ __launch_bounds__(256) void rowsum_kernel(const float* __restrict__ x0,
                                                     const float* __restrict__ x1,
                                                     float* __restrict__ rowsum) {
    const int gtid = blockIdx.x * 256 + threadIdx.x;
    const int wave = gtid >> 6;        // global row index
    const int lane = threadIdx.x & 63;

    const float4* src = (wave < ROWS0)
        ? (const float4*)(x0 + (size_t)wave * T_SZ)
        : (const float4*)(x1 + (size_t)(wave - ROWS0) * T_SZ);

    float sum = 0.0f;
#pragma unroll
    for (int it = 0; it < 16; ++it) {
        float4 v = src[it * 64 + lane];
        sum += (v.x + v.y) + (v.z + v.w);
    }
#pragma unroll
    for (int off = 32; off > 0; off >>= 1)
        sum += __shfl_down(sum, off, 64);

    if (lane == 0)
        rowsum[wave] = sum;
}

// ---------------------------------------------------------------------------
// Kernel 2: FINAL attention weights, one block per batch b (grid=8, 256 thr).
//   gap[c] = (sum of 7 block-row sums)/T ; h = relu(BN(gap@W1+b1));
//   sc[k]  = h @ Wh[k,:,c] + bh[k,c] ; att = softmax_k(sc)   (LOWEST=0)
// ---------------------------------------------------------------------------
__global__ __launch_bounds__(256) void att_kernel(const float* __restrict__ rowsum,
                                                  const float* __restrict__ W1,
                                                  const float* __restrict__ b1,
                                                  const float* __restrict__ gamma,
                                                  const float* __restrict__ beta,
                                                  const float* __restrict__ Wh,
                                                  const float* __restrict__ bh,
                                                  float* __restrict__ att) {
    __shared__ float s_gap[BC];
    __shared__ float s_h[RC];
    const int tid = threadIdx.x;
    const int b = blockIdx.x;

    float s = 0.0f;
#pragma unroll
    for (int blk = 0; blk < NB0; ++blk)
        s += rowsum[b * 1024 + blk * 256 + tid];
#pragma unroll
    for (int blk = 0; blk < NB1; ++blk)
        s += rowsum[ROWS0 + b * 768 + blk * 256 + tid];
    s_gap[tid] = s * (1.0f / (float)T_SZ);
    __syncthreads();

    if (tid < RC) {
        const float bnscale = rsqrtf(1.0f + 1e-5f);
        float acc = 0.0f;
#pragma unroll 8
        for (int c = 0; c < BC; ++c)
            acc = fmaf(s_gap[c], W1[c * RC + tid], acc);
        acc += b1[tid];
        acc = acc * (gamma[tid] * bnscale) + beta[tid];
        s_h[tid] = fmaxf(acc, 0.0f);
    }
    __syncthreads();

    float sc[TB];
#pragma unroll
    for (int k = 0; k < TB; ++k)
        sc[k] = bh[k * BC + tid];
    for (int r = 0; r < RC; ++r) {
        const float hr = s_h[r];
#pragma unroll
        for (int k = 0; k < TB; ++k)
            sc[k] = fmaf(Wh[(k * RC + r) * BC + tid], hr, sc[k]);
    }
    float mx = -1e30f;
#pragma unroll
    for (int k = 0; k < TB; ++k) mx = fmaxf(mx, sc[k]);
    float sum = 0.0f;
#pragma unroll
    for (int k = 0; k < TB; ++k) { sc[k] = __expf(sc[k] - mx); sum += sc[k]; }
    const float inv = 1.0f / sum;
#pragma unroll
    for (int k = 0; k < TB; ++k)
        att[(b * TB + k) * BC + tid] = sc[k] * inv;
}

// ---------------------------------------------------------------------------
// Kernel 3: scale each row by its attention scalar. 4 rows/block, one wave
// per row. Nontemporal loads (last use of x) + nontemporal stores
// (write-once output; avoids evicting x from L3 before its re-read).
// ---------------------------------------------------------------------------
__global__ __launch_bounds__(256) void scale_kernel(const float* __restrict__ x0,
                                                    const float* __restrict__ x1,
                                                    const float* __restrict__ att,
                                                    float* __restrict__ out) {
    const int row = blockIdx.x * 4 + (threadIdx.x >> 6);
    const int lane = threadIdx.x & 63;
    const vfloat4* src;
    vfloat4* dst;
    float a;
    if (row < ROWS0) {
        const int b = row >> 10;
        const int ch = row & 1023;
        a = att[(b * TB + (ch >> 8)) * BC + (ch & 255)];
        src = (const vfloat4*)(x0 + (size_t)row * T_SZ);
        dst = (vfloat4*)(out + (size_t)row * T_SZ);
    } else {
        const int r = row - ROWS0;
        const int b = (int)((unsigned)r / 768u);
        const int ch = r - b * 768;
        a = att[(b * TB + NB0 + (ch >> 8)) * BC + (ch & 255)];
        src = (const vfloat4*)(x1 + (size_t)r * T_SZ);
        dst = (vfloat4*)(out + X0_ELEMS + (size_t)r * T_SZ);
    }
#pragma unroll
    for (int it = 0; it < 16; ++it) {
        vfloat4 v = __builtin_nontemporal_load(&src[it * 64 + lane]);
        v *= a;
        __builtin_nontemporal_store(v, &dst[it * 64 + lane]);
    }
}

extern "C" void kernel_launch(void* const* d_in, const int* in_sizes, int n_in,
                              void* d_out, int out_size, void* d_ws, size_t ws_size,
                              hipStream_t stream) {
    const float* x0    = (const float*)d_in[0];
    const float* x1    = (const float*)d_in[1];
    const float* W1    = (const float*)d_in[2];
    const float* b1    = (const float*)d_in[3];
    const float* gamma = (const float*)d_in[4];
    const float* beta  = (const float*)d_in[5];
    const float* Wh    = (const float*)d_in[6];
    const float* bh    = (const float*)d_in[7];
    float* out = (float*)d_out;

    float* rowsum = out;           // scratch in out-prefix (consumed by att)
    float* att = (float*)d_ws;     // 56 KiB, within proven workspace budget

    // --- duplicated launches: measurement, not optimization ---
    // rowsum x2: second launch rewrites identical values before att reads.
    // scale  x2: second launch rewrites identical outputs.
    // dur(R8) - dur(R5) = rowsum_dur + scale_dur.
    rowsum_kernel<<<ROWS_TOTAL / 4, 256, 0, stream>>>(x0, x1, rowsum);
    rowsum_kernel<<<ROWS_TOTAL / 4, 256, 0, stream>>>(x0, x1, rowsum);
    att_kernel<<<B_SZ, 256, 0, stream>>>(rowsum, W1, b1, gamma, beta, Wh, bh, att);
    scale_kernel<<<ROWS_TOTAL / 4, 256, 0, stream>>>(x0, x1, att, out);
    scale_kernel<<<ROWS_TOTAL / 4, 256, 0, stream>>>(x0, x1, att, out);
}